// Round 12
// baseline (137.824 us; speedup 1.0000x reference)
//
#include <hip/hip_runtime.h>
#include <hip/hip_bf16.h>

#define N_FEATS 128
#define SCAN_CHUNK 1024   // elements per scan block (256 thr x 4)

typedef __attribute__((ext_vector_type(8))) short bf16x8;
typedef __attribute__((ext_vector_type(4))) float f32x4;

__device__ __forceinline__ unsigned short f32_to_bf16_rne(float f) {
    unsigned u = __float_as_uint(f);
    u = u + 0x7FFFu + ((u >> 16) & 1u);   // round-to-nearest-even
    return (unsigned short)(u >> 16);
}
__device__ __forceinline__ unsigned pack2(float a, float b) {
    return (unsigned)f32_to_bf16_rne(a) | ((unsigned)f32_to_bf16_rne(b) << 16);
}

// ---------------------------------------------------------------------------
// Transform (tier A2): Y[m][o] = bf16( sum_k feature[m][k] * W[o][k] )
// Per block: cast W fp32 -> bf16 into LDS (XOR-swizzled, G4: 16 lanes read
// 16 different rows at the same col-block -> swizzle or 16-way conflict).
// 4 waves/block, 16 rows/wave. Also zeroes deg[] with spare thread range.
// mfma_f32_16x16x32_bf16 mapping (m89-verified): A row=l&15, k-chunk=l>>4;
// B col=l&15, k-chunk=l>>4; C/D col=l&15, row=(l>>4)*4+reg.
// ---------------------------------------------------------------------------
__launch_bounds__(256)
__global__ void gcn_transform_mfma(const float* __restrict__ feat,
                                   const float* __restrict__ W,
                                   unsigned short* __restrict__ Y,
                                   int* __restrict__ deg, int n_nodes) {
    __shared__ unsigned short wlds[N_FEATS * N_FEATS];   // 32 KB, swizzled

    const int t = threadIdx.x;
    const long long gid = (long long)blockIdx.x * 256 + t;
    if (gid < n_nodes) deg[gid] = 0;                     // fold deg memset

    // ---- cast W into LDS: thread t covers row t>>1, col half (t&1)*64 ----
    {
        const int row = t >> 1;
        const int gbase = (t & 1) * 8;                   // 16B-granule base
        const float* wsrc = W + (size_t)row * N_FEATS + gbase * 8;
#pragma unroll
        for (int g = 0; g < 8; ++g) {
            float4 x0 = *reinterpret_cast<const float4*>(wsrc + g * 8);
            float4 x1 = *reinterpret_cast<const float4*>(wsrc + g * 8 + 4);
            uint4 q;
            q.x = pack2(x0.x, x0.y);
            q.y = pack2(x0.z, x0.w);
            q.z = pack2(x1.x, x1.y);
            q.w = pack2(x1.z, x1.w);
            int byte = row * 256 + (gbase + g) * 16;
            byte ^= (row & 7) << 4;                      // same swizzle as read
            *reinterpret_cast<uint4*>(reinterpret_cast<char*>(wlds) + byte) = q;
        }
    }
    __syncthreads();

    const int row0 = (blockIdx.x * 4 + (t >> 6)) * 16;
    if (row0 >= n_nodes) return;
    const int l = t & 63;
    const int lr = l & 15;        // A row within stripe / B,D column
    const int kb = l >> 4;        // k-block 0..3 (8 k each)

    // ---- A frags: row row0+lr, inline fp32 -> bf16 cast ----
    bf16x8 afrag[4] = {};
    if (row0 + lr < n_nodes) {
        const float* aptr = feat + (size_t)(row0 + lr) * N_FEATS + kb * 8;
#pragma unroll
        for (int kk = 0; kk < 4; ++kk) {
            float4 x0 = *reinterpret_cast<const float4*>(aptr + kk * 32);
            float4 x1 = *reinterpret_cast<const float4*>(aptr + kk * 32 + 4);
            bf16x8 af;
            af[0] = (short)f32_to_bf16_rne(x0.x);
            af[1] = (short)f32_to_bf16_rne(x0.y);
            af[2] = (short)f32_to_bf16_rne(x0.z);
            af[3] = (short)f32_to_bf16_rne(x0.w);
            af[4] = (short)f32_to_bf16_rne(x1.x);
            af[5] = (short)f32_to_bf16_rne(x1.y);
            af[6] = (short)f32_to_bf16_rne(x1.z);
            af[7] = (short)f32_to_bf16_rne(x1.w);
            afrag[kk] = af;
        }
    }

    f32x4 acc[8];
#pragma unroll
    for (int nt = 0; nt < 8; ++nt) acc[nt] = (f32x4){0.f, 0.f, 0.f, 0.f};

#pragma unroll
    for (int nt = 0; nt < 8; ++nt) {
        const int brow = nt * 16 + lr;
        const int swz = (brow & 7) << 4;
#pragma unroll
        for (int kk = 0; kk < 4; ++kk) {
            int byte = brow * 256 + (kk * 4 + kb) * 16;
            byte ^= swz;
            bf16x8 bfrag = *reinterpret_cast<const bf16x8*>(
                reinterpret_cast<const char*>(wlds) + byte);
            acc[nt] = __builtin_amdgcn_mfma_f32_16x16x32_bf16(afrag[kk], bfrag, acc[nt], 0, 0, 0);
        }
    }

    // ---- epilogue: store Y bf16 ----
#pragma unroll
    for (int nt = 0; nt < 8; ++nt) {
        const int col = nt * 16 + lr;
#pragma unroll
        for (int j = 0; j < 4; ++j) {
            const int r = row0 + kb * 4 + j;
            if (r < n_nodes)
                Y[(size_t)r * N_FEATS + col] = f32_to_bf16_rne(acc[nt][j]);
        }
    }
}

// ---------------------------------------------------------------------------
// CSR pass 1: histogram AND per-edge slot position (guards both indices).
// ---------------------------------------------------------------------------
__global__ void gcn_hist_pos(const int* __restrict__ src, const int* __restrict__ dst,
                             int* __restrict__ deg, int* __restrict__ pos,
                             int n_edges, int n_nodes) {
    int e = blockIdx.x * blockDim.x + threadIdx.x;
    if (e >= n_edges) return;
    int d = dst[e];
    int s = src[e];
    if ((unsigned)d < (unsigned)n_nodes && (unsigned)s < (unsigned)n_nodes)
        pos[e] = atomicAdd(&deg[d], 1);
}

// ---------------------------------------------------------------------------
// Fused scan (single kernel): block b sums deg[0 .. b*1024) for its chunk
// offset (<=200KB seq read), then exclusive-scans its own chunk.
// Last block writes row_start[n].
// ---------------------------------------------------------------------------
__launch_bounds__(256)
__global__ void gcn_scan(const int* __restrict__ deg, int* __restrict__ row_start,
                         int n, int nchunks) {
    const int t = threadIdx.x;
    const int b = blockIdx.x;
    const int base = b * SCAN_CHUNK;

    // ---- chunk offset: sum of deg[0..base) ----
    int v = 0;
    for (int j = t; j < base; j += 256) v += deg[j];
    for (int d = 1; d < 64; d <<= 1) v += __shfl_xor(v, d, 64);
    __shared__ int owsum[4];
    __shared__ int s_off;
    if ((t & 63) == 0) owsum[t >> 6] = v;
    __syncthreads();
    if (t == 0) s_off = owsum[0] + owsum[1] + owsum[2] + owsum[3];
    __syncthreads();
    const int chunk_off = s_off;

    // ---- per-chunk exclusive scan (4 elems / thread) ----
    const int idx0 = base + t * 4;
    int x[4];
#pragma unroll
    for (int k = 0; k < 4; ++k) {
        int idx = idx0 + k;
        x[k] = (idx < n) ? deg[idx] : 0;
    }
    const int tsum = x[0] + x[1] + x[2] + x[3];

    const int lane = t & 63, w = t >> 6;
    int inc = tsum;
    for (int d = 1; d < 64; d <<= 1) {
        int sv = __shfl_up(inc, d, 64);
        if (lane >= d) inc += sv;
    }
    __shared__ int wsum[4];
    if (lane == 63) wsum[w] = inc;
    __syncthreads();
    int woff = 0;
    for (int i = 0; i < w; ++i) woff += wsum[i];

    int run = chunk_off + woff + inc - tsum;
#pragma unroll
    for (int k = 0; k < 4; ++k) {
        int idx = idx0 + k;
        if (idx < n) row_start[idx] = run;
        run += x[k];
    }

    if (t == 0 && b == nchunks - 1)
        row_start[n] = chunk_off + wsum[0] + wsum[1] + wsum[2] + wsum[3];
}

// ---------------------------------------------------------------------------
// CSR scatter, atomic-free (uses precomputed pos).
// ---------------------------------------------------------------------------
__global__ void gcn_build_csr_pos(const int* __restrict__ src, const int* __restrict__ dst,
                                  const int* __restrict__ row_start, const int* __restrict__ pos,
                                  int* __restrict__ csr_src, int n_edges, int n_nodes) {
    int e = blockIdx.x * blockDim.x + threadIdx.x;
    if (e >= n_edges) return;
    int d = dst[e];
    int s = src[e];
    if ((unsigned)d >= (unsigned)n_nodes || (unsigned)s >= (unsigned)n_nodes) return;
    csr_src[row_start[d] + pos[e]] = s;
}

// ---------------------------------------------------------------------------
// Split aggregation + bias (tier A2): one wave per (node, feature-half).
// half = (wave >= n_nodes); in-order dispatch keeps the 6.4MB half-table as
// the working set per phase (higher L2 hit). Eighth-wave (8 lanes x 16B)
// per 128B half-row, 8 edges/instr, x2 unroll = 16 edges in flight.
// fp32 accumulate, shfl_xor 8/16/32 combine, + bias, fp32 out.
// ---------------------------------------------------------------------------
#define BACC(acc, v)                                              \
    do {                                                          \
        unsigned uu;                                              \
        uu = (v).x;                                               \
        acc[0] += __uint_as_float(uu << 16);                      \
        acc[1] += __uint_as_float(uu & 0xFFFF0000u);              \
        uu = (v).y;                                               \
        acc[2] += __uint_as_float(uu << 16);                      \
        acc[3] += __uint_as_float(uu & 0xFFFF0000u);              \
        uu = (v).z;                                               \
        acc[4] += __uint_as_float(uu << 16);                      \
        acc[5] += __uint_as_float(uu & 0xFFFF0000u);              \
        uu = (v).w;                                               \
        acc[6] += __uint_as_float(uu << 16);                      \
        acc[7] += __uint_as_float(uu & 0xFFFF0000u);              \
    } while (0)

__launch_bounds__(256)
__global__ void gcn_aggregate_half(const uint4* __restrict__ Y,
                                   const int* __restrict__ row_start,
                                   const int* __restrict__ csr_src,
                                   const float* __restrict__ bias,
                                   float* __restrict__ out, int n_nodes) {
    const int wid = blockIdx.x * 4 + (threadIdx.x >> 6);
    const int half = (wid >= n_nodes) ? 1 : 0;
    const int node = wid - half * n_nodes;
    if (node >= n_nodes) return;
    const int l = threadIdx.x & 63;
    const int g = l >> 3;        // edge group 0..7
    const int ql = l & 7;        // 16B chunk within 128B half-row
    const int beg = row_start[node];
    const int end = row_start[node + 1];
    const int coff = half * 8 + ql;   // uint4 col offset within row (stride 16)

    float a0[8] = {0,0,0,0,0,0,0,0};
    float a1[8] = {0,0,0,0,0,0,0,0};

    int i = beg;
    for (; i + 16 <= end; i += 16) {             // 16 edges per iter
        int s0 = csr_src[i + g];
        int s1 = csr_src[i + 8 + g];
        uint4 v0 = Y[(size_t)s0 * 16 + coff];
        uint4 v1 = Y[(size_t)s1 * 16 + coff];
        BACC(a0, v0);
        BACC(a1, v1);
    }
    if (i + 8 <= end) {                          // one remaining full group
        int s0 = csr_src[i + g];
        uint4 v0 = Y[(size_t)s0 * 16 + coff];
        BACC(a0, v0);
        i += 8;
    }
    int rem = end - i;                           // <8 leftover edges
    if (g < rem) {
        int s0 = csr_src[i + g];
        uint4 v0 = Y[(size_t)s0 * 16 + coff];
        BACC(a0, v0);
    }

    float r[8];
#pragma unroll
    for (int k = 0; k < 8; ++k) {
        r[k] = a0[k] + a1[k];
        r[k] += __shfl_xor(r[k], 8, 64);
        r[k] += __shfl_xor(r[k], 16, 64);
        r[k] += __shfl_xor(r[k], 32, 64);
    }

    if (g == 0) {                                // lanes 0..7 write 64 floats
        const int cbase = half * 64 + ql * 8;
        const float4 b0 = *reinterpret_cast<const float4*>(bias + cbase);
        const float4 b1 = *reinterpret_cast<const float4*>(bias + cbase + 4);
        float4* o4 = reinterpret_cast<float4*>(out + (size_t)node * N_FEATS + cbase);
        o4[0] = make_float4(r[0] + b0.x, r[1] + b0.y, r[2] + b0.z, r[3] + b0.w);
        o4[1] = make_float4(r[4] + b1.x, r[5] + b1.y, r[6] + b1.z, r[7] + b1.w);
    }
}

// ---------------------------------------------------------------------------
// Tier C fallback: transpose-W init, atomic scatter-add, fp32 GEMM.
// ---------------------------------------------------------------------------
__global__ void gcn_init_c(const float* __restrict__ W, float* __restrict__ Wt) {
    int t = blockIdx.x * blockDim.x + threadIdx.x;
    if (t < N_FEATS * N_FEATS) {
        int o = t >> 7;
        int i = t & 127;
        Wt[i * N_FEATS + o] = W[o * N_FEATS + i];
    }
}

__global__ void gcn_scatter_add(const float* __restrict__ feat,
                                const int* __restrict__ src,
                                const int* __restrict__ dst,
                                float* __restrict__ agg,
                                int n_edges, int n_nodes) {
    long long tid = (long long)blockIdx.x * blockDim.x + threadIdx.x;
    int e = (int)(tid >> 5);
    if (e >= n_edges) return;
    int j = (int)(tid & 31);
    int s = src[e];
    int d = dst[e];
    if ((unsigned)s >= (unsigned)n_nodes || (unsigned)d >= (unsigned)n_nodes) return;
    const float4 v = *reinterpret_cast<const float4*>(feat + (size_t)s * N_FEATS + j * 4);
    float* p = agg + (size_t)d * N_FEATS + j * 4;
    atomicAdd(p + 0, v.x);
    atomicAdd(p + 1, v.y);
    atomicAdd(p + 2, v.z);
    atomicAdd(p + 3, v.w);
}

__launch_bounds__(256)
__global__ void gcn_gemm_inplace(float* __restrict__ out,
                                 const float* __restrict__ Wt,
                                 const float* __restrict__ b,
                                 int n_nodes) {
    __shared__ float a_lds[32 * N_FEATS];   // 16 KB

    const int t = threadIdx.x;
    const int node0 = blockIdx.x * 32;
    const int rows = min(32, n_nodes - node0);

    float4* a4 = reinterpret_cast<float4*>(a_lds);
    const float4* out4 = reinterpret_cast<const float4*>(out + (size_t)node0 * N_FEATS);
    const int nflt4 = rows * (N_FEATS / 4);
    for (int idx = t; idx < nflt4; idx += 256) a4[idx] = out4[idx];
    __syncthreads();

    const int oq = t & 31;
    const int ng = t >> 5;

    const float4 bb = reinterpret_cast<const float4*>(b)[oq];
    float4 acc[4];
#pragma unroll
    for (int k = 0; k < 4; ++k) acc[k] = bb;

    const float4* Wt4 = reinterpret_cast<const float4*>(Wt);
#pragma unroll 4
    for (int i = 0; i < N_FEATS; ++i) {
        const float4 w = Wt4[i * 32 + oq];
#pragma unroll
        for (int k = 0; k < 4; ++k) {
            const float a = a_lds[(ng * 4 + k) * N_FEATS + i];
            acc[k].x += a * w.x;
            acc[k].y += a * w.y;
            acc[k].z += a * w.z;
            acc[k].w += a * w.w;
        }
    }

    __syncthreads();

#pragma unroll
    for (int k = 0; k < 4; ++k) {
        const int r = ng * 4 + k;
        if (r < rows) {
            reinterpret_cast<float4*>(out + (size_t)(node0 + r) * N_FEATS)[oq] = acc[k];
        }
    }
}

extern "C" void kernel_launch(void* const* d_in, const int* in_sizes, int n_in,
                              void* d_out, int out_size, void* d_ws, size_t ws_size,
                              hipStream_t stream) {
    const float* feature = (const float*)d_in[0];
    const int*   src     = (const int*)d_in[1];
    const int*   dst     = (const int*)d_in[2];
    const float* W       = (const float*)d_in[3];
    const float* b       = (const float*)d_in[4];
    float* out = (float*)d_out;

    const int n_nodes = in_sizes[0] / N_FEATS;
    const int n_edges = in_sizes[1];
    const int nchunks = (n_nodes + SCAN_CHUNK - 1) / SCAN_CHUNK;

    // ---- workspace layout (256 B aligned) ----
    char* ws = (char*)d_ws;
    size_t off = 0;
    auto take = [&](size_t bytes) -> char* {
        char* p = ws + off;
        off = (off + bytes + 255) & ~(size_t)255;
        return p;
    };
    int* deg       = (int*)take((size_t)n_nodes * sizeof(int));
    int* row_start = (int*)take(((size_t)n_nodes + 1) * sizeof(int));
    int* csr_src   = (int*)take((size_t)n_edges * sizeof(int));
    unsigned short* Yb = (unsigned short*)take((size_t)n_nodes * N_FEATS * sizeof(unsigned short));
    int* pos       = (int*)take((size_t)n_edges * sizeof(int));
    const bool tierA2 = (off <= ws_size);

    if (tierA2) {
        // 1. transform: feature @ W^T -> Y (bf16), + deg zero, W cast in LDS
        gcn_transform_mfma<<<(n_nodes + 63) / 64, 256, 0, stream>>>(
            feature, W, Yb, deg, n_nodes);
        // 2. histogram + per-edge position
        const int eblocks = (n_edges + 255) / 256;
        gcn_hist_pos<<<eblocks, 256, 0, stream>>>(src, dst, deg, pos, n_edges, n_nodes);
        // 3. fused scan -> row_start
        gcn_scan<<<nchunks, 256, 0, stream>>>(deg, row_start, n_nodes, nchunks);
        // 4. atomic-free CSR scatter
        gcn_build_csr_pos<<<eblocks, 256, 0, stream>>>(
            src, dst, row_start, pos, csr_src, n_edges, n_nodes);
        // 5. split aggregation + bias
        const int nwaves = 2 * n_nodes;
        gcn_aggregate_half<<<(nwaves + 3) / 4, 256, 0, stream>>>(
            reinterpret_cast<const uint4*>(Yb), row_start, csr_src, b, out, n_nodes);
    } else {
        // tier C: transpose init + atomic scatter + fp32 GEMM
        float* Wt = (float*)d_ws;   // 64 KB
        gcn_init_c<<<(N_FEATS * N_FEATS + 255) / 256, 256, 0, stream>>>(W, Wt);
        hipMemsetAsync(d_out, 0, (size_t)n_nodes * N_FEATS * sizeof(float), stream);
        long long total = (long long)n_edges * 32;
        gcn_scatter_add<<<(int)((total + 255) / 256), 256, 0, stream>>>(
            feature, src, dst, out, n_edges, n_nodes);
        gcn_gemm_inplace<<<(n_nodes + 31) / 32, 256, 0, stream>>>(out, Wt, b, n_nodes);
    }
}